// Round 5
// baseline (494.537 us; speedup 1.0000x reference)
//
#include <hip/hip_runtime.h>
#include <math.h>

constexpr int Bc = 8, Nc = 2048, Dc = 256;
constexpr int BN = Bc * Nc; // 16384

typedef __attribute__((ext_vector_type(8))) short short8;
typedef __attribute__((ext_vector_type(4))) float f32x4;

__device__ __forceinline__ float sigmoidf_(float x) { return 1.0f / (1.0f + expf(-x)); }

__device__ __forceinline__ unsigned short f2bf(float f) { // RNE fp32 -> bf16
    unsigned int u = __float_as_uint(f);
    u = (u + 0x7FFFu + ((u >> 16) & 1u)) >> 16;
    return (unsigned short)u;
}
__device__ __forceinline__ float bf2f(unsigned short s) {
    return __uint_as_float(((unsigned int)s) << 16);
}

// 8-elem bf16 fragment: elems 0..3 at base[0..3], elems 4..7 at base[16..19].
// k-slot bijection slot(g16,e): e<4 -> g16*4+e ; e>=4 -> 16+g16*4+(e-4).
// A and B both use it => consistent pairing (any bijection valid).
__device__ __forceinline__ short8 ld_frag(const unsigned short* base) {
    ushort4 lo = *(const ushort4*)(base);
    ushort4 hi = *(const ushort4*)(base + 16);
    short8 a;
    a[0] = (short)lo.x; a[1] = (short)lo.y; a[2] = (short)lo.z; a[3] = (short)lo.w;
    a[4] = (short)hi.x; a[5] = (short)hi.y; a[6] = (short)hi.z; a[7] = (short)hi.w;
    return a;
}
__device__ __forceinline__ f32x4 fz4() { f32x4 z = {0.f, 0.f, 0.f, 0.f}; return z; }

// ---------------- cast feat fp32 -> bf16 ----------------
__global__ __launch_bounds__(256) void cast_kernel(const float* __restrict__ f,
                                                   unsigned short* __restrict__ o) {
    int i = (blockIdx.x * 256 + threadIdx.x) * 4;
    float4 v = *(const float4*)(f + i);
    ushort4 u = {f2bf(v.x), f2bf(v.y), f2bf(v.z), f2bf(v.w)};
    *(ushort4*)(o + i) = u;
}

// ---------------- pack BmT[512 n][256 k] bf16 = [ W | Hw^T ]^T ----------------
__global__ __launch_bounds__(256) void pack_bt_kernel(const float* __restrict__ W,
                                                      const float* __restrict__ Hw,
                                                      unsigned short* __restrict__ BmT) {
    int idx = blockIdx.x * 256 + threadIdx.x;
    int o = idx >> 8, k = idx & 255;
    float v = (o < 256) ? W[k * 256 + o] : Hw[(o - 256) * 256 + k];
    BmT[idx] = f2bf(v);
}

// ---------------- MFMA GEMM: C(16384x512) = featb @ BmT^T ; h | gate epilogue ----------------
__global__ __launch_bounds__(256) void gemm_mfma(const unsigned short* __restrict__ featb,
                                                 const unsigned short* __restrict__ BmT,
                                                 const float* __restrict__ Hb,
                                                 float* __restrict__ h,
                                                 float* __restrict__ gate) {
    const int tid = threadIdx.x, lane = tid & 63, w = tid >> 6;
    const int g16 = lane >> 4, li = lane & 15;
    const int m0 = blockIdx.x * 64, nw = blockIdx.y * 128 + w * 32;
    f32x4 acc[4][2];
#pragma unroll
    for (int rf = 0; rf < 4; ++rf)
#pragma unroll
        for (int cf = 0; cf < 2; ++cf) acc[rf][cf] = fz4();
    for (int k0 = 0; k0 < 256; k0 += 32) {
        short8 Af[4];
#pragma unroll
        for (int rf = 0; rf < 4; ++rf)
            Af[rf] = ld_frag(featb + (size_t)(m0 + rf * 16 + li) * 256 + k0 + g16 * 4);
#pragma unroll
        for (int cf = 0; cf < 2; ++cf) {
            short8 Bf = ld_frag(BmT + (size_t)(nw + cf * 16 + li) * 256 + k0 + g16 * 4);
#pragma unroll
            for (int rf = 0; rf < 4; ++rf)
                acc[rf][cf] = __builtin_amdgcn_mfma_f32_16x16x32_bf16(Af[rf], Bf, acc[rf][cf], 0, 0, 0);
        }
    }
#pragma unroll
    for (int rf = 0; rf < 4; ++rf)
#pragma unroll
        for (int cf = 0; cf < 2; ++cf) {
            const int n = nw + cf * 16 + li;
#pragma unroll
            for (int reg = 0; reg < 4; ++reg) {
                const int m = m0 + rf * 16 + g16 * 4 + reg;
                float v = acc[rf][cf][reg];
                if (n < 256) h[(size_t)m * 256 + n] = v;
                else gate[(size_t)m * 256 + (n - 256)] = sigmoidf_(v + Hb[n - 256]);
            }
        }
}

// ---------------- transpose-cast h->hT  +  a_src/a_dst partial dots  +  mean partials ----------------
__global__ __launch_bounds__(256) void tr64f_kernel(const float* __restrict__ h,
                                                    const float* __restrict__ Ws,
                                                    unsigned short* __restrict__ hT,
                                                    float* __restrict__ a_src,
                                                    float* __restrict__ a_dst,
                                                    float* __restrict__ mean_h) {
    __shared__ float tile[64][65];
    const int j0 = blockIdx.x * 64, d0 = blockIdx.y * 64, b = blockIdx.z;
    const int tid = threadIdx.x;
#pragma unroll
    for (int p = 0; p < 16; ++p) {
        int idx = tid + p * 256;
        int jl = idx >> 6, dl = idx & 63;
        tile[jl][dl] = h[((size_t)b * Nc + j0 + jl) * 256 + d0 + dl];
    }
    __syncthreads();
#pragma unroll
    for (int p = 0; p < 16; ++p) {
        int idx = tid + p * 256;
        int dl = idx >> 6, jl = idx & 63;
        hT[((size_t)b * 256 + d0 + dl) * Nc + j0 + jl] = f2bf(tile[jl][dl]);
    }
    { // a_src/a_dst partial dot: thread = (row jl, quarter q of 16 d's)
        const int jl = tid >> 2, q = tid & 3;
        float s1 = 0.f, s2 = 0.f;
#pragma unroll
        for (int e = 0; e < 16; ++e) {
            const float hv = tile[jl][q * 16 + e];
            s1 = fmaf(hv, Ws[d0 + q * 16 + e], s1);
            s2 = fmaf(hv, Ws[256 + d0 + q * 16 + e], s2);
        }
        s1 += __shfl_xor(s1, 1); s1 += __shfl_xor(s1, 2);
        s2 += __shfl_xor(s2, 1); s2 += __shfl_xor(s2, 2);
        if (q == 0) {
            atomicAdd(&a_src[b * Nc + j0 + jl], s1);
            atomicAdd(&a_dst[b * Nc + j0 + jl], s2);
        }
    }
    { // mean partial: thread = (d-col dl, 16-row part)
        const int dl = tid & 63, part = tid >> 6;
        float sm = 0.f;
#pragma unroll
        for (int e = 0; e < 16; ++e) sm += tile[part * 16 + e][dl];
        atomicAdd(&mean_h[b * 256 + d0 + dl], sm);
    }
}

// ---------------- fused: scores + I_A + MFMA P@h + normalize/ELU/gate + zero-fill ----------------
__global__ __launch_bounds__(256) void score_fused(
    const int* __restrict__ adj, const unsigned short* __restrict__ hT,
    const float* __restrict__ a_src, const float* __restrict__ a_dst,
    const float* __restrict__ bs_p, const float* __restrict__ bvec,
    const float* __restrict__ gate, const float* __restrict__ feat,
    const float* __restrict__ mean_h, float* __restrict__ out1,
    float* __restrict__ out2) {
    __shared__ float sh_sum[32];
    const int bid = blockIdx.x;
    const int b = bid & 7, ib = bid >> 3; // batch -> XCD affinity; all 512 blocks resident
    const int i0 = ib * 32;
    const int tid = threadIdx.x, lane = tid & 63, w = tid >> 6;
    const int g16 = lane >> 4, li = lane & 15;
    const float bsv = bs_p[0];

    const float as0 = a_src[b * Nc + i0 + li];
    const float as1 = a_src[b * Nc + i0 + 16 + li];

    const int* adjb = adj + (size_t)b * Nc * Nc;
    const float* adb = a_dst + b * Nc;
    const unsigned short* hTb = hT + (size_t)b * 256 * Nc;

    f32x4 acc[2][4];
#pragma unroll
    for (int rf = 0; rf < 2; ++rf)
#pragma unroll
        for (int cf = 0; cf < 4; ++cf) acc[rf][cf] = fz4();
    float rs0 = 0.f, rs1 = 0.f;

#define LOADT(T, AJ, AD)                                                              \
    {                                                                                 \
        const int jq = (T) * 32;                                                      \
        AJ[0][0] = *(const int4*)(adjb + (size_t)(i0 + li) * Nc + jq + g16 * 4);      \
        AJ[0][1] = *(const int4*)(adjb + (size_t)(i0 + li) * Nc + jq + 16 + g16 * 4); \
        AJ[1][0] = *(const int4*)(adjb + (size_t)(i0 + 16 + li) * Nc + jq + g16 * 4); \
        AJ[1][1] = *(const int4*)(adjb + (size_t)(i0 + 16 + li) * Nc + jq + 16 + g16 * 4); \
        AD[0] = *(const float4*)(adb + jq + g16 * 4);                                 \
        AD[1] = *(const float4*)(adb + jq + 16 + g16 * 4);                            \
    }

    int4 aj[2][2]; float4 ad[2];
    LOADT(0, aj, ad);
    for (int t = 0; t <= ib; ++t) {
        int4 cj[2][2] = {{aj[0][0], aj[0][1]}, {aj[1][0], aj[1][1]}};
        float4 cd[2] = {ad[0], ad[1]};
        if (t < ib) LOADT(t + 1, aj, ad);
        const int j0 = t * 32;
        short8 A[2];
        if (t < ib) { // fully strictly-lower tile
#pragma unroll
            for (int rf = 0; rf < 2; ++rf) {
                const float asr = rf ? as1 : as0;
                float o2[8];
#pragma unroll
                for (int e = 0; e < 8; ++e) {
                    const int a_ = (e < 4) ? ((const int*)&cj[rf][0])[e] : ((const int*)&cj[rf][1])[e - 4];
                    const float adv = (e < 4) ? ((const float*)&cd[0])[e] : ((const float*)&cd[1])[e - 4];
                    const float IA = -sigmoidf_(asr + adv + bsv);
                    const float p = (a_ == 1) ? expf(IA - 1.f) : 0.f;
                    const unsigned short pb = f2bf(p);
                    A[rf][e] = (short)pb;
                    const float pr = bf2f(pb);
                    if (rf == 0) rs0 += pr; else rs1 += pr;
                    o2[e] = IA;
                }
                if (w == 0) {
                    const int irow = i0 + rf * 16 + li;
                    float4 v0 = {o2[0], o2[1], o2[2], o2[3]};
                    float4 v1 = {o2[4], o2[5], o2[6], o2[7]};
                    *(float4*)(out2 + ((size_t)b * Nc + irow) * Nc + j0 + g16 * 4) = v0;
                    *(float4*)(out2 + ((size_t)b * Nc + irow) * Nc + j0 + 16 + g16 * 4) = v1;
                }
            }
        } else { // diagonal tile: per-element select for j vs i
#pragma unroll
            for (int rf = 0; rf < 2; ++rf) {
                const int irow = i0 + rf * 16 + li;
                const float asr = rf ? as1 : as0;
                float o2[8];
#pragma unroll
                for (int e = 0; e < 8; ++e) {
                    const int j = j0 + ((e < 4) ? (g16 * 4 + e) : (16 + g16 * 4 + e - 4));
                    const int a_ = (e < 4) ? ((const int*)&cj[rf][0])[e] : ((const int*)&cj[rf][1])[e - 4];
                    const float adv = (e < 4) ? ((const float*)&cd[0])[e] : ((const float*)&cd[1])[e - 4];
                    const float IA = -sigmoidf_(asr + adv + bsv);
                    float o2v, p;
                    if (j > irow)       { o2v = 0.f; p = 0.f; }
                    else if (j == irow) { o2v = 1.f; p = (a_ == 1) ? 1.f : 0.f; }
                    else                { o2v = IA;  p = (a_ == 1) ? expf(IA - 1.f) : 0.f; }
                    const unsigned short pb = f2bf(p);
                    A[rf][e] = (short)pb;
                    const float pr = bf2f(pb);
                    if (rf == 0) rs0 += pr; else rs1 += pr;
                    o2[e] = o2v;
                }
                if (w == 0) {
                    float4 v0 = {o2[0], o2[1], o2[2], o2[3]};
                    float4 v1 = {o2[4], o2[5], o2[6], o2[7]};
                    *(float4*)(out2 + ((size_t)b * Nc + irow) * Nc + j0 + g16 * 4) = v0;
                    *(float4*)(out2 + ((size_t)b * Nc + irow) * Nc + j0 + 16 + g16 * 4) = v1;
                }
            }
        }
#pragma unroll
        for (int cf = 0; cf < 4; ++cf) {
            short8 Bf = ld_frag(hTb + (size_t)(w * 64 + cf * 16 + li) * Nc + j0 + g16 * 4);
            acc[0][cf] = __builtin_amdgcn_mfma_f32_16x16x32_bf16(A[0], Bf, acc[0][cf], 0, 0, 0);
            acc[1][cf] = __builtin_amdgcn_mfma_f32_16x16x32_bf16(A[1], Bf, acc[1][cf], 0, 0, 0);
        }
    }
#undef LOADT
    // row sums: reduce over g16 lanes (disjoint k-slots)
    rs0 += __shfl_xor(rs0, 16); rs0 += __shfl_xor(rs0, 32);
    rs1 += __shfl_xor(rs1, 16); rs1 += __shfl_xor(rs1, 32);
    if (w == 0 && g16 == 0) { sh_sum[li] = rs0; sh_sum[16 + li] = rs1; }
    __syncthreads();

    { // fused epilogue: normalize / mean-fallback, +b, ELU, gate mix
        const float invN = 1.0f / Nc;
#pragma unroll
        for (int rf = 0; rf < 2; ++rf)
#pragma unroll
            for (int cf = 0; cf < 4; ++cf) {
                const int col = w * 64 + cf * 16 + li;
                const float bb = bvec[col];
#pragma unroll
                for (int reg = 0; reg < 4; ++reg) {
                    const int row = i0 + rf * 16 + g16 * 4 + reg;
                    const float s = sh_sum[rf * 16 + g16 * 4 + reg];
                    const size_t g = ((size_t)b * Nc + row) * 256 + col;
                    float v = (s == 0.f) ? mean_h[b * 256 + col] * invN : acc[rf][cf][reg] / s;
                    v += bb;
                    v = v > 0.f ? v : expf(v) - 1.f;
                    const float gt = gate[g];
                    out1[g] = gt * v + (1.f - gt) * feat[g];
                }
            }
    }
    { // zero-fill upper tail of I_A_raw (cols >= i0+32)
        const int jstart4 = (i0 + 32) >> 2;
        const float4 z = make_float4(0.f, 0.f, 0.f, 0.f);
        for (int r = 0; r < 32; ++r) {
            float4* rowp = (float4*)(out2 + ((size_t)b * Nc + i0 + r) * Nc);
            for (int j4 = jstart4 + tid; j4 < Nc / 4; j4 += 256) rowp[j4] = z;
        }
    }
}

extern "C" void kernel_launch(void* const* d_in, const int* in_sizes, int n_in,
                              void* d_out, int out_size, void* d_ws, size_t ws_size,
                              hipStream_t stream) {
    const float* feat = (const float*)d_in[0];
    const int* adj = (const int*)d_in[1];
    const float* W = (const float*)d_in[2];
    const float* bvec = (const float*)d_in[3];
    const float* Ws = (const float*)d_in[4];
    const float* bs = (const float*)d_in[5];
    const float* Hw = (const float*)d_in[6];
    const float* Hb = (const float*)d_in[7];

    float* ws = (float*)d_ws;
    unsigned short* featb = (unsigned short*)ws; // bf16 16384x256; reused as hT after gemm
    unsigned short* hT = featb;
    unsigned short* BmT = featb + 4194304;       // bf16 512x256
    float* h = ws + 2097152 + 65536;             // fp32 16384x256
    float* gate = h + 4194304;                   // fp32 16384x256
    float* a_src = gate + 4194304;               // 16384
    float* a_dst = a_src + 16384;                // 16384
    float* mean_h = a_dst + 16384;               // 2048

    float* out1 = (float*)d_out;
    float* out2 = out1 + (size_t)BN * 256;

    hipLaunchKernelGGL(cast_kernel, dim3(4096), dim3(256), 0, stream, feat, featb);
    hipLaunchKernelGGL(pack_bt_kernel, dim3(512), dim3(256), 0, stream, W, Hw, BmT);
    hipLaunchKernelGGL(gemm_mfma, dim3(256, 4), dim3(256), 0, stream, featb, BmT, Hb, h, gate);
    hipMemsetAsync(a_src, 0, (16384 + 16384 + 2048) * sizeof(float), stream); // a_src|a_dst|mean_h
    hipLaunchKernelGGL(tr64f_kernel, dim3(32, 4, 8), dim3(256), 0, stream,
                       h, Ws, hT, a_src, a_dst, mean_h);
    hipLaunchKernelGGL(score_fused, dim3(512), dim3(256), 0, stream,
                       adj, hT, a_src, a_dst, bs, bvec, gate, feat, mean_h, out1, out2);
}